// Round 1
// baseline (167.789 us; speedup 1.0000x reference)
//
#include <hip/hip_runtime.h>
#include <cstdint>

#define E_CNT 131072
#define N_CNT 4096
#define R_CNT 8
#define B_CNT 30
#define H_CNT 64
#define C_CNT 16

typedef short bf16x8 __attribute__((ext_vector_type(8)));
typedef float f32x4 __attribute__((ext_vector_type(4)));

__device__ __forceinline__ ushort f2bf(float f) {
  union { float f; unsigned u; } v; v.f = f;
  unsigned r = v.u + 0x7FFFu + ((v.u >> 16) & 1u);
  return (ushort)(r >> 16);
}

// ---------------- zero helper ----------------
__global__ __launch_bounds__(256) void k_zero(int* __restrict__ p) {
  p[blockIdx.x * 256 + threadIdx.x] = 0;
}

// ---------------- x fp32 -> bf16 ----------------
__global__ __launch_bounds__(256) void k_cvt_x(const float4* __restrict__ x,
                                               ushort* __restrict__ xbf) {
  int i = blockIdx.x * 256 + threadIdx.x;
  float4 v = x[i];
  ushort4 o;
  o.x = f2bf(v.x); o.y = f2bf(v.y); o.z = f2bf(v.z); o.w = f2bf(v.w);
  *(ushort4*)(xbf + (size_t)i * 4) = o;
}

// ---------------- degree histogram ----------------
__global__ __launch_bounds__(256) void k_deg(const int* __restrict__ dstp,
                                             int* __restrict__ deg) {
  int e = blockIdx.x * 256 + threadIdx.x;
  atomicAdd(&deg[dstp[e]], 1);
}

// ---------------- exclusive scan over 4096 degrees (1 block, 1024 thr) ----
__global__ __launch_bounds__(1024) void k_scan(const int* __restrict__ deg,
                                               int* __restrict__ rowptr,
                                               int* __restrict__ cursor,
                                               float* __restrict__ dinv) {
  __shared__ int part[1024];
  int t = threadIdx.x;
  int base = t * 4;
  int d0 = deg[base], d1 = deg[base + 1], d2 = deg[base + 2], d3 = deg[base + 3];
  int s = d0 + d1 + d2 + d3;
  part[t] = s;
  __syncthreads();
  for (int off = 1; off < 1024; off <<= 1) {
    int v = part[t];
    int u = (t >= off) ? part[t - off] : 0;
    __syncthreads();
    part[t] = v + u;
    __syncthreads();
  }
  int incl = part[t];
  int excl = incl - s;
  int p0 = excl, p1 = excl + d0, p2 = p1 + d1, p3 = p2 + d2;
  rowptr[base] = p0; rowptr[base + 1] = p1; rowptr[base + 2] = p2; rowptr[base + 3] = p3;
  cursor[base] = p0; cursor[base + 1] = p1; cursor[base + 2] = p2; cursor[base + 3] = p3;
  dinv[base]     = 1.0f / fmaxf((float)d0, 1.0f);
  dinv[base + 1] = 1.0f / fmaxf((float)d1, 1.0f);
  dinv[base + 2] = 1.0f / fmaxf((float)d2, 1.0f);
  dinv[base + 3] = 1.0f / fmaxf((float)d3, 1.0f);
  if (t == 1023) rowptr[4096] = incl;
}

// ---------------- CSR fill (src,etype packed) ----------------
__global__ __launch_bounds__(256) void k_fill(const int* __restrict__ srcp,
                                              const int* __restrict__ dstp,
                                              const int* __restrict__ et,
                                              int* __restrict__ cursor,
                                              int* __restrict__ spack) {
  int e = blockIdx.x * 256 + threadIdx.x;
  int d = dstp[e];
  int pos = atomicAdd(&cursor[d], 1);
  spack[pos] = (srcp[e] << 3) | et[e];
}

// ---------------- Wtmp[r][i][o] = sum_b att1[r,b]*basis1[b,i,o] -----------
__global__ __launch_bounds__(256) void k_wtmp(const float* __restrict__ att1,
                                              const float* __restrict__ basis1,
                                              float* __restrict__ wtmp) {
  int flat = blockIdx.x * 256 + threadIdx.x;  // i*64 + o, 262144 total
  float acc[8] = {0.f, 0.f, 0.f, 0.f, 0.f, 0.f, 0.f, 0.f};
  for (int b = 0; b < B_CNT; ++b) {
    float v = basis1[(size_t)b * 262144 + flat];
#pragma unroll
    for (int r = 0; r < 8; ++r) acc[r] += att1[r * 30 + b] * v;
  }
#pragma unroll
  for (int r = 0; r < 8; ++r) wtmp[(size_t)r * 262144 + flat] = acc[r];
}

// ------ transpose+convert: Wt1[r*64+o][i] (bf16), r=8 row block = root1 ---
__global__ __launch_bounds__(256) void k_transw(const float* __restrict__ wtmp,
                                                const float* __restrict__ root1,
                                                ushort* __restrict__ wt1) {
  __shared__ float tile[64 * 65];
  int r = blockIdx.x >> 6;          // 0..8
  int i0 = (blockIdx.x & 63) * 64;  // i tile
  const float* srcp = (r < 8) ? (wtmp + (size_t)r * N_CNT * H_CNT) : root1;
  int t = threadIdx.x;
#pragma unroll
  for (int it = 0; it < 16; ++it) {
    int flat = it * 256 + t;
    int il = flat >> 6, o = flat & 63;
    tile[il * 65 + o] = srcp[(size_t)(i0 + il) * 64 + o];
  }
  __syncthreads();
#pragma unroll
  for (int it = 0; it < 16; ++it) {
    int flat = it * 256 + t;
    int o = flat >> 6, il = flat & 63;
    wt1[(size_t)(r * 64 + o) * 4096 + i0 + il] = f2bf(tile[il * 65 + o]);
  }
}

// ---------------- big GEMM: C1[4096][576] = xbf @ Wt1^T -------------------
// BM=128, BN=64, BK=64, 256 thr (4 waves 2x2), wave tile 64x32.
__global__ __launch_bounds__(256) void k_gemm1(const ushort* __restrict__ xbf,
                                               const ushort* __restrict__ wt1,
                                               float* __restrict__ c1) {
  __shared__ __align__(16) ushort As[128 * 64];
  __shared__ __align__(16) ushort Bs[64 * 64];
  int bid = blockIdx.x;
  int swz = (bid & 7) * 36 + (bid >> 3);  // 288 = 8*36, bijective XCD swizzle
  int bm = swz / 9, bn = swz % 9;
  int m0 = bm * 128, n0 = bn * 64;
  int tid = threadIdx.x;
  int lane = tid & 63, wid = tid >> 6;
  int wm = wid >> 1, wn = wid & 1;

  f32x4 acc[4][2] = {};

  for (int k0 = 0; k0 < 4096; k0 += 64) {
    // stage A: 128x64 bf16 = 16KB = 4 iters * 256 lanes * 16B
#pragma unroll
    for (int it = 0; it < 4; ++it) {
      int flat = it * 256 + tid;
      int row = flat >> 3, c8 = (flat & 7) << 3;
      const ushort* g = xbf + (size_t)(m0 + row) * 4096 + k0 + c8;
      ushort* l = &As[(size_t)(it * 256 + wid * 64) * 8];
      __builtin_amdgcn_global_load_lds((const __attribute__((address_space(1))) void*)g,
                                       (__attribute__((address_space(3))) void*)l, 16, 0, 0);
    }
    // stage B: 64x64 bf16 = 8KB = 2 iters
#pragma unroll
    for (int it = 0; it < 2; ++it) {
      int flat = it * 256 + tid;
      int row = flat >> 3, c8 = (flat & 7) << 3;
      const ushort* g = wt1 + (size_t)(n0 + row) * 4096 + k0 + c8;
      ushort* l = &Bs[(size_t)(it * 256 + wid * 64) * 8];
      __builtin_amdgcn_global_load_lds((const __attribute__((address_space(1))) void*)g,
                                       (__attribute__((address_space(3))) void*)l, 16, 0, 0);
    }
    __syncthreads();
#pragma unroll
    for (int ks = 0; ks < 2; ++ks) {
      bf16x8 bfr[2];
#pragma unroll
      for (int ni = 0; ni < 2; ++ni)
        bfr[ni] = *(const bf16x8*)&Bs[(wn * 32 + ni * 16 + (lane & 15)) * 64 + ks * 32 + (lane >> 4) * 8];
#pragma unroll
      for (int mi = 0; mi < 4; ++mi) {
        bf16x8 afr = *(const bf16x8*)&As[(wm * 64 + mi * 16 + (lane & 15)) * 64 + ks * 32 + (lane >> 4) * 8];
#pragma unroll
        for (int ni = 0; ni < 2; ++ni)
          acc[mi][ni] = __builtin_amdgcn_mfma_f32_16x16x32_bf16(afr, bfr[ni], acc[mi][ni], 0, 0, 0);
      }
    }
    __syncthreads();
  }
  int cf = lane & 15, rf4 = (lane >> 4) * 4;
#pragma unroll
  for (int mi = 0; mi < 4; ++mi)
#pragma unroll
    for (int ni = 0; ni < 2; ++ni) {
      int gcol = n0 + wn * 32 + ni * 16 + cf;
#pragma unroll
      for (int j = 0; j < 4; ++j) {
        int grow = m0 + wm * 64 + mi * 16 + rf4 + j;
        c1[(size_t)grow * 576 + gcol] = acc[mi][ni][j];
      }
    }
}

// ---------------- layer-1 aggregate + root + bias + relu ------------------
__global__ __launch_bounds__(64) void k_agg1(const float* __restrict__ c1,
                                             const int* __restrict__ rowptr,
                                             const int* __restrict__ spack,
                                             const float* __restrict__ dinv,
                                             const float* __restrict__ bias1,
                                             float* __restrict__ h) {
  int n = blockIdx.x, t = threadIdx.x;  // t = feature h
  int s0 = rowptr[n], s1 = rowptr[n + 1];
  float acc = 0.f;
  for (int e = s0; e < s1; ++e) {
    int p = spack[e];
    acc += c1[(size_t)(p >> 3) * 576 + (p & 7) * 64 + t];
  }
  float v = acc * dinv[n] + c1[(size_t)n * 576 + 512 + t] + bias1[t];
  h[n * 64 + t] = fmaxf(v, 0.f);
}

// ---------------- W2e[r][h][c], r=8 -> root2 ------------------------------
__global__ __launch_bounds__(256) void k_w2e(const float* __restrict__ att2,
                                             const float* __restrict__ basis2,
                                             const float* __restrict__ root2,
                                             float* __restrict__ w2e) {
  int r = blockIdx.x;  // 0..8
  for (int t = threadIdx.x; t < 1024; t += 256) {
    float acc = 0.f;
    if (r < 8) {
      for (int b = 0; b < B_CNT; ++b) acc += att2[r * 30 + b] * basis2[b * 1024 + t];
    } else {
      acc = root2[t];
    }
    w2e[r * 1024 + t] = acc;
  }
}

// ---------------- h2c[n][rc] rc: 0..127 = r*16+c, 128..143 = root ---------
__global__ __launch_bounds__(256) void k_h2(const float* __restrict__ h,
                                            const float* __restrict__ w2e,
                                            float* __restrict__ h2c) {
  int flat = blockIdx.x * 256 + threadIdx.x;  // 4096*144 exact
  int n = flat / 144, rc = flat % 144;
  int r9 = rc >> 4, c = rc & 15;  // rc>=128 -> r9==8 (root block)
  const float* hr = h + (size_t)n * 64;
  const float* w = w2e + r9 * 1024 + c;
  float acc = 0.f;
#pragma unroll
  for (int hh = 0; hh < 64; ++hh) acc += hr[hh] * w[hh * 16];
  h2c[flat] = acc;
}

// ---------------- layer-2 aggregate + root + bias + log_softmax -----------
__global__ __launch_bounds__(64) void k_agg2(const float* __restrict__ h2c,
                                             const int* __restrict__ rowptr,
                                             const int* __restrict__ spack,
                                             const float* __restrict__ dinv,
                                             const float* __restrict__ bias2,
                                             float* __restrict__ out) {
  __shared__ float red[64];
  int n = blockIdx.x, t = threadIdx.x;
  int c = t & 15, q = t >> 4;
  int s0 = rowptr[n], s1 = rowptr[n + 1];
  float acc = 0.f;
  for (int e = s0 + q; e < s1; e += 4) {
    int p = spack[e];
    acc += h2c[(size_t)(p >> 3) * 144 + (p & 7) * 16 + c];
  }
  red[t] = acc;
  __syncthreads();
  if (t < 16) {
    float sum = red[c] + red[16 + c] + red[32 + c] + red[48 + c];
    float v = sum * dinv[n] + h2c[(size_t)n * 144 + 128 + c] + bias2[c];
    float m = v;
#pragma unroll
    for (int off = 1; off < 16; off <<= 1) m = fmaxf(m, __shfl_xor(m, off, 64));
    float ex = expf(v - m);
    float s = ex;
#pragma unroll
    for (int off = 1; off < 16; off <<= 1) s += __shfl_xor(s, off, 64);
    out[n * 16 + c] = v - m - logf(s);
  }
}

extern "C" void kernel_launch(void* const* d_in, const int* in_sizes, int n_in,
                              void* d_out, int out_size, void* d_ws, size_t ws_size,
                              hipStream_t stream) {
  const float* x      = (const float*)d_in[0];
  const int*   ei     = (const int*)d_in[1];
  const int*   et     = (const int*)d_in[2];
  const float* basis1 = (const float*)d_in[3];
  const float* att1   = (const float*)d_in[4];
  const float* root1  = (const float*)d_in[5];
  const float* bias1  = (const float*)d_in[6];
  const float* basis2 = (const float*)d_in[7];
  const float* att2   = (const float*)d_in[8];
  const float* root2  = (const float*)d_in[9];
  const float* bias2  = (const float*)d_in[10];
  float* out = (float*)d_out;

  char* ws = (char*)d_ws;
  size_t off = 0;
  auto alloc = [&](size_t bytes) {
    void* p = ws + off;
    off = (off + bytes + 255) & ~(size_t)255;
    return p;
  };
  ushort* xbf  = (ushort*)alloc((size_t)N_CNT * N_CNT * 2);
  ushort* wt1  = (ushort*)alloc((size_t)576 * 4096 * 2);
  float*  wtmp = (float*)alloc((size_t)8 * N_CNT * H_CNT * 4);
  float*  c1   = (float*)alloc((size_t)N_CNT * 576 * 4);
  float*  hbuf = (float*)alloc((size_t)N_CNT * 64 * 4);
  float*  w2e  = (float*)alloc((size_t)9 * 64 * 16 * 4);
  float*  h2c  = (float*)alloc((size_t)N_CNT * 144 * 4);
  int*    deg    = (int*)alloc(4096 * 4);
  float*  dinv   = (float*)alloc(4096 * 4);
  int*    rowptr = (int*)alloc(4097 * 4);
  int*    cursor = (int*)alloc(4096 * 4);
  int*    spack  = (int*)alloc((size_t)E_CNT * 4);

  const int* srcp = ei;
  const int* dstp = ei + E_CNT;

  k_zero<<<16, 256, 0, stream>>>(deg);
  k_cvt_x<<<16384, 256, 0, stream>>>((const float4*)x, xbf);
  k_deg<<<512, 256, 0, stream>>>(dstp, deg);
  k_wtmp<<<1024, 256, 0, stream>>>(att1, basis1, wtmp);
  k_scan<<<1, 1024, 0, stream>>>(deg, rowptr, cursor, dinv);
  k_fill<<<512, 256, 0, stream>>>(srcp, dstp, et, cursor, spack);
  k_transw<<<576, 256, 0, stream>>>(wtmp, root1, wt1);
  k_gemm1<<<288, 256, 0, stream>>>(xbf, wt1, c1);
  k_agg1<<<4096, 64, 0, stream>>>(c1, rowptr, spack, dinv, bias1, hbuf);
  k_w2e<<<9, 256, 0, stream>>>(att2, basis2, root2, w2e);
  k_h2<<<2304, 256, 0, stream>>>(hbuf, w2e, h2c);
  k_agg2<<<4096, 64, 0, stream>>>(h2c, rowptr, spack, dinv, bias2, out);
}

// Round 2
// 158.269 us; speedup vs baseline: 1.0601x; 1.0601x over previous
//
#include <hip/hip_runtime.h>
#include <cstdint>

#define E_CNT 131072
#define N_CNT 4096

typedef short bf16x8 __attribute__((ext_vector_type(8)));
typedef float f32x4 __attribute__((ext_vector_type(4)));

__device__ __forceinline__ ushort f2bf(float f) {
  union { float f; unsigned u; } v; v.f = f;
  unsigned r = v.u + 0x7FFFu + ((v.u >> 16) & 1u);
  return (ushort)(r >> 16);
}

// ---------------- tiny zero for deg ----------------
__global__ __launch_bounds__(256) void k_zero_deg(int* __restrict__ p) {
  p[blockIdx.x * 256 + threadIdx.x] = 0;
}

// ---------------- fused prep: cvt_x | deg-hist | wtmp | c1-zero -----------
// blocks [0,16384): x fp32->bf16 ; [16384,16896): degree histogram ;
// [16896,17920): wtmp basis combine ; [17920,27136): zero c1
__global__ __launch_bounds__(256) void k_prep(const float4* __restrict__ x,
                                              ushort* __restrict__ xbf,
                                              const int* __restrict__ dstp,
                                              int* __restrict__ deg,
                                              const float* __restrict__ att1,
                                              const float* __restrict__ basis1,
                                              float* __restrict__ wtmp,
                                              int* __restrict__ c1i) {
  int bid = blockIdx.x, tid = threadIdx.x;
  if (bid < 16384) {
    int i = bid * 256 + tid;
    float4 v = x[i];
    ushort4 o;
    o.x = f2bf(v.x); o.y = f2bf(v.y); o.z = f2bf(v.z); o.w = f2bf(v.w);
    *(ushort4*)(xbf + (size_t)i * 4) = o;
  } else if (bid < 16896) {
    int e = (bid - 16384) * 256 + tid;
    atomicAdd(&deg[dstp[e]], 1);
  } else if (bid < 17920) {
    int flat = (bid - 16896) * 256 + tid;  // i*64+o
    float a[8] = {0.f, 0.f, 0.f, 0.f, 0.f, 0.f, 0.f, 0.f};
    for (int b = 0; b < 30; ++b) {
      float v = basis1[(size_t)b * 262144 + flat];
#pragma unroll
      for (int r = 0; r < 8; ++r) a[r] += att1[r * 30 + b] * v;
    }
#pragma unroll
    for (int r = 0; r < 8; ++r) wtmp[(size_t)r * 262144 + flat] = a[r];
  } else {
    int flat = (bid - 17920) * 256 + tid;  // < 2359296 = 4096*576
    c1i[flat] = 0;
  }
}

// ---------------- exclusive scan over 4096 degrees (1 block) --------------
__global__ __launch_bounds__(1024) void k_scan(const int* __restrict__ deg,
                                               int* __restrict__ rowptr,
                                               int* __restrict__ cursor,
                                               float* __restrict__ dinv) {
  __shared__ int part[1024];
  int t = threadIdx.x;
  int base = t * 4;
  int d0 = deg[base], d1 = deg[base + 1], d2 = deg[base + 2], d3 = deg[base + 3];
  int s = d0 + d1 + d2 + d3;
  part[t] = s;
  __syncthreads();
  for (int off = 1; off < 1024; off <<= 1) {
    int v = part[t];
    int u = (t >= off) ? part[t - off] : 0;
    __syncthreads();
    part[t] = v + u;
    __syncthreads();
  }
  int incl = part[t];
  int excl = incl - s;
  int p0 = excl, p1 = excl + d0, p2 = p1 + d1, p3 = p2 + d2;
  rowptr[base] = p0; rowptr[base + 1] = p1; rowptr[base + 2] = p2; rowptr[base + 3] = p3;
  cursor[base] = p0; cursor[base + 1] = p1; cursor[base + 2] = p2; cursor[base + 3] = p3;
  dinv[base]     = 1.0f / fmaxf((float)d0, 1.0f);
  dinv[base + 1] = 1.0f / fmaxf((float)d1, 1.0f);
  dinv[base + 2] = 1.0f / fmaxf((float)d2, 1.0f);
  dinv[base + 3] = 1.0f / fmaxf((float)d3, 1.0f);
  if (t == 1023) rowptr[4096] = incl;
}

// ---------------- fused mid: CSR-fill | transpose W1 | W2 combine ---------
// blocks [0,512): fill ; [512,1088): transw ; [1088,1097): w2e
__global__ __launch_bounds__(256) void k_mid(const int* __restrict__ srcp,
                                             const int* __restrict__ dstp,
                                             const int* __restrict__ et,
                                             int* __restrict__ cursor,
                                             int* __restrict__ spack,
                                             const float* __restrict__ wtmp,
                                             const float* __restrict__ root1,
                                             ushort* __restrict__ wt1,
                                             const float* __restrict__ att2,
                                             const float* __restrict__ basis2,
                                             const float* __restrict__ root2,
                                             float* __restrict__ w2e) {
  __shared__ float tile[64 * 65];
  int bid = blockIdx.x, t = threadIdx.x;
  if (bid < 512) {
    int e = bid * 256 + t;
    int d = dstp[e];
    int pos = atomicAdd(&cursor[d], 1);
    spack[pos] = (srcp[e] << 3) | et[e];
  } else if (bid < 1088) {
    int bb = bid - 512;
    int r = bb >> 6;                // 0..8
    int i0 = (bb & 63) * 64;
    const float* sp = (r < 8) ? (wtmp + (size_t)r * 262144) : root1;
#pragma unroll
    for (int it = 0; it < 16; ++it) {
      int flat = it * 256 + t;
      int il = flat >> 6, o = flat & 63;
      tile[il * 65 + o] = sp[(size_t)(i0 + il) * 64 + o];
    }
    __syncthreads();
#pragma unroll
    for (int it = 0; it < 16; ++it) {
      int flat = it * 256 + t;
      int o = flat >> 6, il = flat & 63;
      wt1[(size_t)(r * 64 + o) * 4096 + i0 + il] = f2bf(tile[il * 65 + o]);
    }
  } else {
    int r = bid - 1088;  // 0..8
    for (int q = t; q < 1024; q += 256) {
      float a = 0.f;
      if (r < 8) {
        for (int b = 0; b < 30; ++b) a += att2[r * 30 + b] * basis2[b * 1024 + q];
      } else {
        a = root2[q];
      }
      w2e[r * 1024 + q] = a;
    }
  }
}

// ---------------- split-K GEMM: c1[4096][576] += xbf @ wt1^T --------------
// BM=128 BN=64 BK=64, SPLITK=4 (Kpart=1024, 16 K-steps), 256 thr (2x2 waves),
// double-buffered LDS + single-barrier 2-phase pipeline, XOR-chunk swizzle.
#define SPLITK 4
#define KSTEPS 16
__global__ __launch_bounds__(256) void k_gemm1(const ushort* __restrict__ xbf,
                                               const ushort* __restrict__ wt1,
                                               float* __restrict__ c1) {
  __shared__ __align__(16) ushort As[2][128 * 64];
  __shared__ __align__(16) ushort Bs[2][64 * 64];
  int bid = blockIdx.x;
  int swz = (bid & 7) * 144 + (bid >> 3);  // 1152 = 8*144, bijective
  int kp = swz / 288, t2 = swz % 288;
  int bm = t2 / 9, bn = t2 % 9;
  int m0 = bm * 128, n0 = bn * 64, kbase = kp * 1024;
  int tid = threadIdx.x;
  int lane = tid & 63, wid = tid >> 6;
  int wm = wid >> 1, wn = wid & 1;

  f32x4 acc[4][2] = {};

  auto stage = [&](int buf, int k0) {
#pragma unroll
    for (int it = 0; it < 4; ++it) {
      int flat = it * 256 + tid;
      int row = flat >> 3, gg = flat & 7;
      int gcol = k0 + ((gg ^ (row & 7)) << 3);  // pre-swizzled source (rule #21)
      const ushort* g = xbf + (size_t)(m0 + row) * 4096 + gcol;
      ushort* l = &As[buf][(it * 256 + wid * 64) * 8];  // linear LDS dest
      __builtin_amdgcn_global_load_lds((const __attribute__((address_space(1))) void*)g,
                                       (__attribute__((address_space(3))) void*)l, 16, 0, 0);
    }
#pragma unroll
    for (int it = 0; it < 2; ++it) {
      int flat = it * 256 + tid;
      int row = flat >> 3, gg = flat & 7;
      int gcol = k0 + ((gg ^ (row & 7)) << 3);
      const ushort* g = wt1 + (size_t)(n0 + row) * 4096 + gcol;
      ushort* l = &Bs[buf][(it * 256 + wid * 64) * 8];
      __builtin_amdgcn_global_load_lds((const __attribute__((address_space(1))) void*)g,
                                       (__attribute__((address_space(3))) void*)l, 16, 0, 0);
    }
  };

  stage(0, kbase);
  __syncthreads();
  int cur = 0;
  for (int t = 0; t < KSTEPS; ++t) {
    if (t + 1 < KSTEPS) stage(cur ^ 1, kbase + (t + 1) * 64);
#pragma unroll
    for (int ks = 0; ks < 2; ++ks) {
      int q = lane >> 4, sw = lane & 7;
      bf16x8 bfr[2];
#pragma unroll
      for (int ni = 0; ni < 2; ++ni) {
        int row = wn * 32 + ni * 16 + (lane & 15);
        bfr[ni] = *(const bf16x8*)&Bs[cur][row * 64 + (((ks * 4 + q) ^ sw) << 3)];
      }
#pragma unroll
      for (int mi = 0; mi < 4; ++mi) {
        int row = wm * 64 + mi * 16 + (lane & 15);
        bf16x8 afr = *(const bf16x8*)&As[cur][row * 64 + (((ks * 4 + q) ^ sw) << 3)];
#pragma unroll
        for (int ni = 0; ni < 2; ++ni)
          acc[mi][ni] = __builtin_amdgcn_mfma_f32_16x16x32_bf16(afr, bfr[ni], acc[mi][ni], 0, 0, 0);
      }
    }
    __syncthreads();  // drains vmcnt(0): next buf staged, cur free for overwrite
    cur ^= 1;
  }

  int cf = lane & 15, rf4 = (lane >> 4) * 4;
#pragma unroll
  for (int mi = 0; mi < 4; ++mi)
#pragma unroll
    for (int ni = 0; ni < 2; ++ni) {
      int gcol = n0 + wn * 32 + ni * 16 + cf;
#pragma unroll
      for (int j = 0; j < 4; ++j) {
        int grow = m0 + wm * 64 + mi * 16 + rf4 + j;
        atomicAdd(&c1[(size_t)grow * 576 + gcol], acc[mi][ni][j]);
      }
    }
}

// ---------------- fused layer-1 aggregate + relu + layer-2 transform ------
__global__ __launch_bounds__(64) void k_agg1h2(const float* __restrict__ c1,
                                               const int* __restrict__ rowptr,
                                               const int* __restrict__ spack,
                                               const float* __restrict__ dinv,
                                               const float* __restrict__ bias1,
                                               const float* __restrict__ w2e,
                                               float* __restrict__ h2c) {
  __shared__ float sh[64];
  int n = blockIdx.x, t = threadIdx.x;  // t = feature h
  int s0 = rowptr[n], s1 = rowptr[n + 1];
  float acc = 0.f;
  for (int e = s0; e < s1; ++e) {
    int p = spack[e];
    acc += c1[(size_t)(p >> 3) * 576 + (p & 7) * 64 + t];
  }
  float v = acc * dinv[n] + c1[(size_t)n * 576 + 512 + t] + bias1[t];
  sh[t] = fmaxf(v, 0.f);
  __syncthreads();
  float* o = h2c + (size_t)n * 144;
  for (int rc = t; rc < 144; rc += 64) {
    int r9 = rc >> 4, c = rc & 15;
    const float* w = w2e + r9 * 1024 + c;
    float a = 0.f;
#pragma unroll
    for (int hh = 0; hh < 64; ++hh) a += sh[hh] * w[hh * 16];
    o[rc] = a;
  }
}

// ---------------- layer-2 aggregate + root + bias + log_softmax -----------
__global__ __launch_bounds__(64) void k_agg2(const float* __restrict__ h2c,
                                             const int* __restrict__ rowptr,
                                             const int* __restrict__ spack,
                                             const float* __restrict__ dinv,
                                             const float* __restrict__ bias2,
                                             float* __restrict__ out) {
  __shared__ float red[64];
  int n = blockIdx.x, t = threadIdx.x;
  int c = t & 15, q = t >> 4;
  int s0 = rowptr[n], s1 = rowptr[n + 1];
  float acc = 0.f;
  for (int e = s0 + q; e < s1; e += 4) {
    int p = spack[e];
    acc += h2c[(size_t)(p >> 3) * 144 + (p & 7) * 16 + c];
  }
  red[t] = acc;
  __syncthreads();
  if (t < 16) {
    float sum = red[c] + red[16 + c] + red[32 + c] + red[48 + c];
    float v = sum * dinv[n] + h2c[(size_t)n * 144 + 128 + c] + bias2[c];
    float m = v;
#pragma unroll
    for (int off = 1; off < 16; off <<= 1) m = fmaxf(m, __shfl_xor(m, off, 64));
    float ex = expf(v - m);
    float s = ex;
#pragma unroll
    for (int off = 1; off < 16; off <<= 1) s += __shfl_xor(s, off, 64);
    out[n * 16 + c] = v - m - logf(s);
  }
}

extern "C" void kernel_launch(void* const* d_in, const int* in_sizes, int n_in,
                              void* d_out, int out_size, void* d_ws, size_t ws_size,
                              hipStream_t stream) {
  const float* x      = (const float*)d_in[0];
  const int*   ei     = (const int*)d_in[1];
  const int*   et     = (const int*)d_in[2];
  const float* basis1 = (const float*)d_in[3];
  const float* att1   = (const float*)d_in[4];
  const float* root1  = (const float*)d_in[5];
  const float* bias1  = (const float*)d_in[6];
  const float* basis2 = (const float*)d_in[7];
  const float* att2   = (const float*)d_in[8];
  const float* root2  = (const float*)d_in[9];
  const float* bias2  = (const float*)d_in[10];
  float* out = (float*)d_out;

  char* ws = (char*)d_ws;
  size_t off = 0;
  auto alloc = [&](size_t bytes) {
    void* p = ws + off;
    off = (off + bytes + 255) & ~(size_t)255;
    return p;
  };
  ushort* xbf  = (ushort*)alloc((size_t)N_CNT * N_CNT * 2);
  ushort* wt1  = (ushort*)alloc((size_t)576 * 4096 * 2);
  float*  wtmp = (float*)alloc((size_t)8 * N_CNT * 64 * 4);
  float*  c1   = (float*)alloc((size_t)N_CNT * 576 * 4);
  float*  w2e  = (float*)alloc((size_t)9 * 64 * 16 * 4);
  float*  h2c  = (float*)alloc((size_t)N_CNT * 144 * 4);
  int*    deg    = (int*)alloc(4096 * 4);
  float*  dinv   = (float*)alloc(4096 * 4);
  int*    rowptr = (int*)alloc(4097 * 4);
  int*    cursor = (int*)alloc(4096 * 4);
  int*    spack  = (int*)alloc((size_t)E_CNT * 4);

  const int* srcp = ei;
  const int* dstp = ei + E_CNT;

  k_zero_deg<<<16, 256, 0, stream>>>(deg);
  k_prep<<<27136, 256, 0, stream>>>((const float4*)x, xbf, dstp, deg,
                                    att1, basis1, wtmp, (int*)c1);
  k_scan<<<1, 1024, 0, stream>>>(deg, rowptr, cursor, dinv);
  k_mid<<<1097, 256, 0, stream>>>(srcp, dstp, et, cursor, spack,
                                  wtmp, root1, wt1, att2, basis2, root2, w2e);
  k_gemm1<<<1152, 256, 0, stream>>>(xbf, wt1, c1);
  k_agg1h2<<<4096, 64, 0, stream>>>(c1, rowptr, spack, dinv, bias1, w2e, h2c);
  k_agg2<<<4096, 64, 0, stream>>>(h2c, rowptr, spack, dinv, bias2, out);
}